// Round 1
// baseline (1676.123 us; speedup 1.0000x reference)
//
#include <hip/hip_runtime.h>
#include <hip/hip_bf16.h>

typedef __attribute__((ext_vector_type(8))) short short8;
typedef __attribute__((ext_vector_type(4))) short short4v;
typedef __attribute__((ext_vector_type(4))) float float4v;
typedef __attribute__((ext_vector_type(4))) float v4f;

constexpr int MDIM = 2048;
constexpr int KDIM = 65536;
constexpr int NPL  = 768;      // N per layer
constexpr int LNUM = 2;
constexpr int BM = 128, BN = 128, BK = 32;
constexpr int KSPLIT = 16;
constexpr int KCHUNK = KDIM / KSPLIT;   // 4096
constexpr int NITER  = KCHUNK / BK;     // 128

// RTNE fp32 -> bf16 bits (inputs are finite random normals; no NaN path needed)
__device__ __forceinline__ short f2bf(float x) {
  unsigned u = __float_as_uint(x);
  u += 0x7fffu + ((u >> 16) & 1u);
  return (short)(u >> 16);
}

// out[b][l][d] = bias[l][d]  (overwrites 0xAA poison; GEMM atomically accumulates on top)
__global__ void init_out(const float* __restrict__ bias, float* __restrict__ out) {
  int i = blockIdx.x * blockDim.x + threadIdx.x;  // one float4 each
  int idx = i * 4;
  int ld = idx % (LNUM * NPL);
  *(float4v*)(out + idx) = *(const float4v*)(bias + ld);
}

__global__ __launch_bounds__(256)
void gemm_split_k(const float* __restrict__ f, const float* __restrict__ W,
                  float* __restrict__ out) {
  const int bx = blockIdx.x;   // m tile 0..15
  const int by = blockIdx.y;   // n tile 0..11  (layer = by/6)
  const int bz = blockIdx.z;   // k chunk 0..15 (slowest dispatch dim -> LLC locality)
  const int tid = threadIdx.x;
  const int lane = tid & 63;
  const int wave = tid >> 6;
  const int wm = (wave >> 1) * 64;   // wave quadrant of 128x128 tile
  const int wn = (wave & 1) * 64;
  const int layer = by / 6;
  const int d0 = (by % 6) * BN;

  const float* __restrict__ Wl = W + (size_t)layer * KDIM * NPL;

  // k-granule-major LDS: [kg][row ^ kg][k&7] -- conflict-free writes AND b128 frag reads
  __shared__ __hip_bfloat16 sA[4][BM][8];  // 8 KiB
  __shared__ __hip_bfloat16 sB[4][BN][8];  // 8 KiB

  // A staging: lanes 0..7 -> k-float4s (256B coalesced per 16 lanes), tid>>3 -> m row
  const int a_kq = tid & 7;
  const int a_m  = tid >> 3;                 // 0..31, 4 passes of +32
  const float* Aptr = f + (size_t)(bx * BM + a_m) * KDIM + (size_t)bz * KCHUNK + a_kq * 4;

  // B staging: lane -> n (coalesced 256B/inst), k strided by NPL rows
  const int b_n  = tid & 127;
  const int b_kg = tid >> 7;                 // 0..1, 2 passes of +2
  const float* Bptr = Wl + (size_t)bz * KCHUNK * NPL + d0 + b_n;

  v4f acc[4][4];
  #pragma unroll
  for (int i = 0; i < 4; ++i)
    #pragma unroll
    for (int j = 0; j < 4; ++j)
      acc[i][j] = (v4f){0.f, 0.f, 0.f, 0.f};

  const int kg_r = lane >> 4;   // fragment k-granule 0..3
  const int r16  = lane & 15;

  for (int it = 0; it < NITER; ++it) {
    const size_t koff = (size_t)it * BK;

    // ---- global loads (issued before barrier; overlap with prior MFMA) ----
    float4v av[4];
    #pragma unroll
    for (int p = 0; p < 4; ++p)
      av[p] = *(const float4v*)(Aptr + (size_t)(p * 32) * KDIM + koff);

    float bv[16];
    #pragma unroll
    for (int p = 0; p < 2; ++p) {
      const int kg = b_kg + p * 2;
      #pragma unroll
      for (int j = 0; j < 8; ++j)
        bv[p * 8 + j] = Bptr[(koff + (size_t)(kg * 8 + j)) * NPL];
    }

    __syncthreads();  // previous iter's fragment reads done

    // ---- stage A: cvt + 8B writes, XOR-swizzled (conflict-free) ----
    {
      const int kg = a_kq >> 1;
      const int half = (a_kq & 1) * 4;
      #pragma unroll
      for (int p = 0; p < 4; ++p) {
        const int m = a_m + p * 32;
        short4v pk;
        #pragma unroll
        for (int e = 0; e < 4; ++e) pk[e] = f2bf(av[p][e]);
        *(short4v*)&sA[kg][m ^ kg][half] = pk;
      }
    }
    // ---- stage B: cvt + full-granule 16B writes (conflict-free) ----
    #pragma unroll
    for (int p = 0; p < 2; ++p) {
      const int kg = b_kg + p * 2;
      short8 pk;
      #pragma unroll
      for (int j = 0; j < 8; ++j) pk[j] = f2bf(bv[p * 8 + j]);
      *(short8*)&sB[kg][b_n ^ kg][0] = pk;
    }

    __syncthreads();

    // ---- fragments + 16 MFMAs per wave ----
    short8 af[4], bfr[4];
    #pragma unroll
    for (int t = 0; t < 4; ++t)
      af[t] = *(const short8*)&sA[kg_r][(wm + t * 16 + r16) ^ kg_r][0];
    #pragma unroll
    for (int t = 0; t < 4; ++t)
      bfr[t] = *(const short8*)&sB[kg_r][(wn + t * 16 + r16) ^ kg_r][0];
    #pragma unroll
    for (int i = 0; i < 4; ++i)
      #pragma unroll
      for (int j = 0; j < 4; ++j)
        acc[i][j] = __builtin_amdgcn_mfma_f32_16x16x32_bf16(af[i], bfr[j], acc[i][j], 0, 0, 0);
  }

  // ---- epilogue: device-scope f32 atomic accumulate into out[b][l][d] ----
  // C/D layout: col = lane&15 (n), row = (lane>>4)*4 + reg (m)   [m89/m91-verified]
  const int colc = lane & 15;
  const int rowb = (lane >> 4) * 4;
  #pragma unroll
  for (int i = 0; i < 4; ++i) {
    #pragma unroll
    for (int j = 0; j < 4; ++j) {
      const int n = d0 + wn + j * 16 + colc;
      #pragma unroll
      for (int r = 0; r < 4; ++r) {
        const int m = bx * BM + wm + i * 16 + rowb + r;
        unsafeAtomicAdd(&out[((size_t)m * LNUM + layer) * NPL + n], acc[i][j][r]);
      }
    }
  }
}

extern "C" void kernel_launch(void* const* d_in, const int* in_sizes, int n_in,
                              void* d_out, int out_size, void* d_ws, size_t ws_size,
                              hipStream_t stream) {
  const float* f    = (const float*)d_in[0];
  const float* W    = (const float*)d_in[1];
  const float* bias = (const float*)d_in[2];
  float* out = (float*)d_out;

  // out_size = 2048*2*768 = 3145728 floats = 786432 float4s
  init_out<<<dim3(786432 / 256), 256, 0, stream>>>(bias, out);

  gemm_split_k<<<dim3(MDIM / BM, (LNUM * NPL) / BN, KSPLIT), 256, 0, stream>>>(f, W, out);
}